// Round 11
// baseline (517.841 us; speedup 1.0000x reference)
//
#include <hip/hip_runtime.h>
#include <hip/hip_bf16.h>
#include <string.h>

// KanGNN. Inputs f32 + int32, output f32.
// R21: (1) fused kernel goes persistent: grid=1280, tiles claimed via
// atomicAdd counter -> kills the 1.22-round tail that held time-avg
// occupancy at 33% (R20: 1563 blocks / 1280 resident); (2) launches 8->5:
// lin_in + repack x2 + binit + counter-zero merged into one prep_kernel
// (independent work, blockIdx-ranged) — each kernel boundary measured
// ~8-10us. Tile->output mapping unchanged -> bit-identical output.
// R20: fused spmm+kan(+final), ping-pong h0->h1. R18/19: spmm 4x unroll.
// R17: final W-in-registers. R16: async global_load_lds B staging.
// R13/14: lane-local A build. R11: binned counting-sort CSR build.

#define N_NODES 100000
#define IN_FEAT 128
#define HID 64
#define OUT_FEAT 40
#define NGRID 8
#define N_EDGES 1600000
#define NELEM (N_NODES * HID)

#define NB 98            // buckets: row >> 10
#define CAP 18432        // per-bucket capacity (mean 16384, sigma ~127)
#define BCHUNK 4096      // edges per bin block
#define BIN_BLOCKS ((N_EDGES + BCHUNK - 1) / BCHUNK)   // 391
#define NTILES ((N_NODES + 63) / 64)                   // 1563
#define FGRID 1280                                     // persistent blocks

using short8 = __attribute__((ext_vector_type(8))) short;
using floatx4 = __attribute__((ext_vector_type(4))) float;
using uintx4 = __attribute__((ext_vector_type(4))) unsigned;

// async 16B/lane global->LDS; lds dest = wave-uniform base + lane*16
#define GLOAD_LDS16(gp, lp)                                                   \
  __builtin_amdgcn_global_load_lds(                                           \
      (const __attribute__((address_space(1))) unsigned*)(gp),                \
      (__attribute__((address_space(3))) unsigned*)(lp), 16, 0, 0)

// f32 -> bf16 RNE, packed pair (lo = c, hi = s)
__device__ __forceinline__ unsigned pack_bf16x2(float c, float s) {
  unsigned uc = __float_as_uint(c);
  unsigned us = __float_as_uint(s);
  uc += 0x7fffu + ((uc >> 16) & 1u);
  us += 0x7fffu + ((us >> 16) & 1u);
  return (uc >> 16) | (us & 0xffff0000u);
}

// same RNE conversion via v_cvt_pk_bf16_f32 (1 instr instead of ~11)
__device__ __forceinline__ unsigned cvtpk_bf16x2(float c, float s) {
  __hip_bfloat162 p = __float22bfloat162_rn(make_float2(c, s));
  unsigned r;
  memcpy(&r, &p, 4);
  return r;
}

// ---------------------------------------------------------------- prep (merged)
// blocks [0,6250): lin_in; [6250,6506): repack c1/c2; 6506: btail + counters.
__global__ __launch_bounds__(256) void prep_kernel(
    const float* __restrict__ x, const float* __restrict__ W,
    const float* __restrict__ b, float* __restrict__ h,
    const float* __restrict__ c1, const float* __restrict__ c2,
    unsigned* __restrict__ Brep1, unsigned* __restrict__ Brep2,
    int* __restrict__ btail, int* __restrict__ ctrs) {
  __shared__ __align__(16) float xs[16 * IN_FEAT];   // 8 KB
  int t = threadIdx.x;
  int nb = blockIdx.x;
  if (nb < 6250) {
    // ---- lin_in (identical to R20's lin_in_kernel) ----
    const float4* xsrc = (const float4*)(x + (size_t)nb * 16 * IN_FEAT);
    float4* xd = (float4*)xs;
    xd[t] = xsrc[t];
    xd[t + 256] = xsrc[t + 256];
    __syncthreads();
    int lane = t & 63, wv = t >> 6;
    float bj = b[lane];
    float a0 = bj, a1 = bj, a2 = bj, a3 = bj;
    const float* xr = xs + wv * 4 * IN_FEAT;
    const float* Wj = W + lane;
#pragma unroll 4
    for (int i4 = 0; i4 < 32; i4++) {
      float4 x0 = *(const float4*)(xr + 0 * IN_FEAT + i4 * 4);
      float4 x1 = *(const float4*)(xr + 1 * IN_FEAT + i4 * 4);
      float4 x2 = *(const float4*)(xr + 2 * IN_FEAT + i4 * 4);
      float4 x3 = *(const float4*)(xr + 3 * IN_FEAT + i4 * 4);
      float w0 = Wj[(i4 * 4 + 0) * HID];
      float w1 = Wj[(i4 * 4 + 1) * HID];
      float w2 = Wj[(i4 * 4 + 2) * HID];
      float w3 = Wj[(i4 * 4 + 3) * HID];
      a0 = fmaf(x0.x, w0, a0); a0 = fmaf(x0.y, w1, a0); a0 = fmaf(x0.z, w2, a0); a0 = fmaf(x0.w, w3, a0);
      a1 = fmaf(x1.x, w0, a1); a1 = fmaf(x1.y, w1, a1); a1 = fmaf(x1.z, w2, a1); a1 = fmaf(x1.w, w3, a1);
      a2 = fmaf(x2.x, w0, a2); a2 = fmaf(x2.y, w1, a2); a2 = fmaf(x2.z, w2, a2); a2 = fmaf(x2.w, w3, a2);
      a3 = fmaf(x3.x, w0, a3); a3 = fmaf(x3.y, w1, a3); a3 = fmaf(x3.z, w2, a3); a3 = fmaf(x3.w, w3, a3);
    }
    size_t nbase = (size_t)nb * 16 + wv * 4;
    h[(nbase + 0) * HID + lane] = a0;
    h[(nbase + 1) * HID + lane] = a1;
    h[(nbase + 2) * HID + lane] = a2;
    h[(nbase + 3) * HID + lane] = a3;
  } else if (nb < 6506) {
    // ---- repack (R16 layout; identical math) ----
    int rb = nb - 6250;                     // 0..255
    const float* coeffs = (rb < 128) ? c1 : c2;
    unsigned* Brep = (rb < 128) ? Brep1 : Brep2;
    int idx = (rb & 127) * 256 + t;         // 0..32767
    int ch = idx >> 13;
    int rem = idx & 8191;
    int blk = rem >> 8;
    int jt = blk >> 3, ks = blk & 7;
    int rem2 = rem & 255;
    int ls = rem2 >> 2;
    int quad = ls >> 4, m_n = ls & 15;
    int jj = rem2 & 3;
    int j = jt * 16 + m_n;
    int r = ks >> 1, km1 = ((ks & 1) << 2) | jj;
    int i = ch * 16 + quad * 4 + r;
    int ws = i * 8 + km1;
    float cc0 = coeffs[(size_t)j * 512 + ws];
    float cc1 = coeffs[32768 + (size_t)j * 512 + ws];
    Brep[idx] = pack_bf16x2(cc0, cc1);
  } else {
    if (t < NB) btail[t] = t * CAP;
    if (t == 128) { ctrs[0] = 0; ctrs[1] = 0; }
  }
}

// ---------------------------------------------------------------- CSR build (R11)
// Pass 1: coarse-bucket counting sort.
__global__ __launch_bounds__(256) void bin_kernel(
    const int* __restrict__ row, const int* __restrict__ col,
    const float* __restrict__ w, int* __restrict__ btail,
    uint2* __restrict__ pack1) {
  __shared__ __align__(16) uint2 stage[BCHUNK];   // 32 KB
  __shared__ int bcnt[NB];
  __shared__ int lbase[NB];
  __shared__ int gbase[NB];
  __shared__ int lcur[NB];
  __shared__ int sc[128];
  int t = threadIdx.x;
  int e0 = blockIdx.x * BCHUNK;
  if (t < NB) bcnt[t] = 0;
  __syncthreads();
  int rloc[16];
#pragma unroll
  for (int q = 0; q < 16; q++) {
    int e = e0 + q * 256 + t;
    int r = (e < N_EDGES) ? row[e] : -1;
    rloc[q] = r;
    if (r >= 0) atomicAdd(&bcnt[r >> 10], 1);
  }
  __syncthreads();
  int c = (t < NB) ? bcnt[t] : 0;
  if (t < 128) sc[t] = c;
  __syncthreads();
  int v = c;
#pragma unroll
  for (int off = 1; off < 128; off <<= 1) {
    int add = (t >= off && t < 128) ? sc[t - off] : 0;
    __syncthreads();
    if (t < 128) sc[t] = v = v + add;
    __syncthreads();
  }
  if (t < NB) {
    lbase[t] = v - c;
    lcur[t] = v - c;
    gbase[t] = atomicAdd(&btail[t], c);
  }
  __syncthreads();
#pragma unroll
  for (int q = 0; q < 16; q++) {
    int e = e0 + q * 256 + t;
    int r = rloc[q];
    if (r >= 0) {
      int p = atomicAdd(&lcur[r >> 10], 1);
      unsigned key = ((unsigned)(r & 1023) << 17) | (unsigned)col[e];
      stage[p] = make_uint2(key, __float_as_uint(w[e]));
    }
  }
  __syncthreads();
  int wv = t >> 6, lane = t & 63;
  for (int b = wv; b < NB; b += 4) {
    int len = bcnt[b], src = lbase[b];
    uint2* dst = pack1 + (size_t)gbase[b];
    for (int i = lane; i < len; i += 64)
      dst[i] = stage[src + i];
  }
}

// Pass 2: one block per bucket -> rowptr + exact scatter.
__global__ __launch_bounds__(256) void bucket_finalize_kernel(
    const int* __restrict__ btail, const uint2* __restrict__ pack1,
    int* __restrict__ rowptr, uint2* __restrict__ pack2) {
  __shared__ int rcnt[1024];
  __shared__ int sc[256];
  __shared__ int binfo[2];
  int b = blockIdx.x, t = threadIdx.x;
  if (t < NB) sc[t] = btail[t] - t * CAP;   // per-bucket counts
  rcnt[t] = 0; rcnt[t + 256] = 0; rcnt[t + 512] = 0; rcnt[t + 768] = 0;
  __syncthreads();
  if (t == 0) {
    int base = 0;
    for (int i = 0; i < b; i++) base += sc[i];
    binfo[0] = base;
    binfo[1] = sc[b];
  }
  __syncthreads();
  int base = binfo[0], len = binfo[1];
  const uint2* rec = pack1 + (size_t)b * CAP;
  for (int i = t; i < len; i += 256)
    atomicAdd(&rcnt[rec[i].x >> 17], 1);
  __syncthreads();
  int c0 = rcnt[4 * t], c1 = rcnt[4 * t + 1], c2 = rcnt[4 * t + 2], c3 = rcnt[4 * t + 3];
  int s4 = c0 + c1 + c2 + c3;
  sc[t] = s4;
  __syncthreads();
  int v = s4;
#pragma unroll
  for (int off = 1; off < 256; off <<= 1) {
    int add = (t >= off) ? sc[t - off] : 0;
    __syncthreads();
    sc[t] = v = v + add;
    __syncthreads();
  }
  int excl = v - s4;
  int p0 = base + excl;
  int p1 = p0 + c0, p2 = p1 + c1, p3 = p2 + c2;
  int r0 = (b << 10) + 4 * t;
  if (r0 + 0 < N_NODES) rowptr[r0 + 0] = p0;
  if (r0 + 1 < N_NODES) rowptr[r0 + 1] = p1;
  if (r0 + 2 < N_NODES) rowptr[r0 + 2] = p2;
  if (r0 + 3 < N_NODES) rowptr[r0 + 3] = p3;
  rcnt[4 * t] = p0; rcnt[4 * t + 1] = p1; rcnt[4 * t + 2] = p2; rcnt[4 * t + 3] = p3;
  __syncthreads();
  for (int i = t; i < len; i += 256) {
    uint2 p = rec[i];
    int pos = atomicAdd(&rcnt[p.x >> 17], 1);
    pack2[pos] = make_uint2(p.x & 0x1FFFFu, p.y);
  }
  if (b == NB - 1 && t == 0) rowptr[N_NODES] = N_EDGES;
}

// ---------------------------------------------------------------- fused spmm + KAN (+ final)
// R21: persistent — blocks claim tiles via atomicAdd(ctr). Per-tile body
// identical to R20 (gather -> s_tile -> KAN via 16 B-quarters -> output).
template <int DO_FINAL>
__global__ __launch_bounds__(256, 4) void fused_spmm_kan_kernel(
    const int* __restrict__ rowptr, const uint2* __restrict__ pack,
    const float* __restrict__ hin, const unsigned* __restrict__ Brep,
    float* __restrict__ outp, const float* __restrict__ Wout,
    int* __restrict__ ctr) {
  __shared__ __align__(16) unsigned Bs[2][2048];   // 2 x 8 KB
  __shared__ __align__(16) float s_tile[64 * 64];  // 16 KB
  __shared__ int tile_sm;
  int t = threadIdx.x;
  int lane = t & 63, wv = t >> 6;
  const char* Gb = (const char*)Brep;
  int m_n = lane & 15, quad = lane >> 4;

  while (true) {
    if (t == 0) tile_sm = atomicAdd(ctr, 1);
    // publishes tile_sm AND protects s_tile/Bs[0] reuse across tiles
    __syncthreads();
    int nb = tile_sm;
    if (nb >= NTILES) break;

    // issue quarter 0 (ch0,jt0) staging; latency hides under the gathers
#pragma unroll
    for (int i = 0; i < 2; i++) {
      int c = wv + 4 * i;
      GLOAD_LDS16(Gb + c * 1024 + lane * 16, (char*)&Bs[0][0] + c * 1024);
    }

    // ---- phase 1: spmm for rows nb*64 + wv*16 + 0..15 ----
    {
      int rpi = nb * 64 + wv * 16 + lane;
      int rp = 0;
      if (lane < 17) rp = rowptr[rpi < N_NODES ? rpi : N_NODES];
      int slot = lane >> 4, f4 = lane & 15;
      const float4* h4 = (const float4*)hin;
      const unsigned long long* packq = (const unsigned long long*)pack;
      for (int i = 0; i < 16; i++) {
        int beg = __shfl(rp, i), end = __shfl(rp, i + 1);
        float4 v = make_float4(0.f, 0.f, 0.f, 0.f);
        for (int e = beg; e < end; e += 16) {
          int i0 = e + slot, i1 = i0 + 4, i2 = i0 + 8, i3 = i0 + 12;
          int c0 = i0 < end ? i0 : end - 1;
          int c1 = i1 < end ? i1 : end - 1;
          int c2 = i2 < end ? i2 : end - 1;
          int c3 = i3 < end ? i3 : end - 1;
          unsigned long long p0 = __builtin_nontemporal_load(packq + c0);
          unsigned long long p1 = __builtin_nontemporal_load(packq + c1);
          unsigned long long p2 = __builtin_nontemporal_load(packq + c2);
          unsigned long long p3 = __builtin_nontemporal_load(packq + c3);
          float4 h0 = h4[(size_t)(unsigned)p0 * 16 + f4];
          float4 h1 = h4[(size_t)(unsigned)p1 * 16 + f4];
          float4 h2 = h4[(size_t)(unsigned)p2 * 16 + f4];
          float4 h3 = h4[(size_t)(unsigned)p3 * 16 + f4];
          float w0 = (i0 < end) ? __uint_as_float((unsigned)(p0 >> 32)) : 0.f;
          float w1 = (i1 < end) ? __uint_as_float((unsigned)(p1 >> 32)) : 0.f;
          float w2 = (i2 < end) ? __uint_as_float((unsigned)(p2 >> 32)) : 0.f;
          float w3 = (i3 < end) ? __uint_as_float((unsigned)(p3 >> 32)) : 0.f;
          v.x = fmaf(w0, h0.x, v.x); v.y = fmaf(w0, h0.y, v.y);
          v.z = fmaf(w0, h0.z, v.z); v.w = fmaf(w0, h0.w, v.w);
          v.x = fmaf(w1, h1.x, v.x); v.y = fmaf(w1, h1.y, v.y);
          v.z = fmaf(w1, h1.z, v.z); v.w = fmaf(w1, h1.w, v.w);
          v.x = fmaf(w2, h2.x, v.x); v.y = fmaf(w2, h2.y, v.y);
          v.z = fmaf(w2, h2.z, v.z); v.w = fmaf(w2, h2.w, v.w);
          v.x = fmaf(w3, h3.x, v.x); v.y = fmaf(w3, h3.y, v.y);
          v.z = fmaf(w3, h3.z, v.z); v.w = fmaf(w3, h3.w, v.w);
        }
#pragma unroll
        for (int off = 16; off < 64; off <<= 1) {
          v.x += __shfl_xor(v.x, off);
          v.y += __shfl_xor(v.y, off);
          v.z += __shfl_xor(v.z, off);
          v.w += __shfl_xor(v.w, off);
        }
        if (slot == 0)
          *(float4*)&s_tile[(wv * 16 + i) * 64 + f4 * 4] = v;
      }
    }
    __syncthreads();   // s_tile complete

    // ---- phase 2: KAN ----
    float4 sv[4];
#pragma unroll
    for (int ch = 0; ch < 4; ch++)
      sv[ch] = *(const float4*)&s_tile[(wv * 16 + m_n) * 64 + ch * 16 + quad * 4];

    floatx4 acc[4];
#pragma unroll
    for (int jt = 0; jt < 4; jt++) acc[jt] = (floatx4){0.f, 0.f, 0.f, 0.f};
    short8 afr[8];

#pragma unroll
    for (int q = 0; q < 16; q++) {
      asm volatile("s_waitcnt vmcnt(0)" ::: "memory");
      __syncthreads();
      if (q < 15) {
        int qq = q + 1;
        const char* gsrc = Gb + (qq >> 2) * 32768 + (qq & 3) * 8192;
        char* ldst = (char*)&Bs[qq & 1][0];
#pragma unroll
        for (int i = 0; i < 2; i++) {
          int c = wv + 4 * i;
          GLOAD_LDS16(gsrc + c * 1024 + lane * 16, ldst + c * 1024);
        }
      }
      if ((q & 3) == 0) {   // build A fragments at the start of each ch
        int ch = q >> 2;
        float ss[4] = {sv[ch].x, sv[ch].y, sv[ch].z, sv[ch].w};
#pragma unroll
        for (int r = 0; r < 4; r++) {
          float s1, c1;
          __sincosf(ss[r], &s1, &c1);
          float ck = c1, sk = s1;
          unsigned wbuf[8];
#pragma unroll
          for (int km1 = 0; km1 < 8; km1++) {
            wbuf[km1] = cvtpk_bf16x2(ck, sk);
            float cn = fmaf(ck, c1, -sk * s1);
            float sn = fmaf(sk, c1, ck * s1);
            ck = cn; sk = sn;
          }
          uintx4 lo = (uintx4){wbuf[0], wbuf[1], wbuf[2], wbuf[3]};
          uintx4 hi = (uintx4){wbuf[4], wbuf[5], wbuf[6], wbuf[7]};
          memcpy(&afr[2 * r], &lo, 16);
          memcpy(&afr[2 * r + 1], &hi, 16);
        }
      }
      const char* Bb = (const char*)&Bs[q & 1][0];
      int jt = q & 3;
#pragma unroll
      for (int ks = 0; ks < 8; ks++) {
        short8 bf = *reinterpret_cast<const short8*>(Bb + ks * 1024 + lane * 16);
        acc[jt] = __builtin_amdgcn_mfma_f32_16x16x32_bf16(afr[ks], bf, acc[jt], 0, 0, 0);
      }
    }

    if (DO_FINAL == 0) {
#pragma unroll
      for (int jt = 0; jt < 4; jt++) {
#pragma unroll
        for (int reg = 0; reg < 4; reg++) {
          int node = nb * 64 + wv * 16 + quad * 4 + reg;
          if (node < N_NODES)
            outp[(size_t)node * HID + jt * 16 + m_n] = acc[jt][reg];
        }
      }
    } else {
      // acc -> s_tile (own-wave rows; sv already consumed)
#pragma unroll
      for (int jt = 0; jt < 4; jt++) {
#pragma unroll
        for (int reg = 0; reg < 4; reg++)
          s_tile[(wv * 16 + quad * 4 + reg) * 64 + jt * 16 + m_n] = acc[jt][reg];
      }
      __syncthreads();
      // ---- final phase (R17): W columns in registers, 2 nodes in flight ----
      bool jvalid = lane < OUT_FEAT;
      int jc = jvalid ? lane : 0;
      float wl[HID];
#pragma unroll
      for (int i2 = 0; i2 < HID; i2++)
        wl[i2] = Wout[i2 * OUT_FEAT + jc];
      int nwbase = nb * 64 + wv * 16;
      for (int ns = 0; ns < 16; ns += 2) {
        const float* h0p = &s_tile[(wv * 16 + ns) * 64];
        const float* h1p = h0p + 64;
        float d0 = 0.f, d1 = 0.f;
#pragma unroll
        for (int i4 = 0; i4 < 16; i4++) {
          float4 a = *(const float4*)(h0p + i4 * 4);
          float4 b = *(const float4*)(h1p + i4 * 4);
          d0 = fmaf(a.x, wl[i4 * 4 + 0], d0);  d1 = fmaf(b.x, wl[i4 * 4 + 0], d1);
          d0 = fmaf(a.y, wl[i4 * 4 + 1], d0);  d1 = fmaf(b.y, wl[i4 * 4 + 1], d1);
          d0 = fmaf(a.z, wl[i4 * 4 + 2], d0);  d1 = fmaf(b.z, wl[i4 * 4 + 2], d1);
          d0 = fmaf(a.w, wl[i4 * 4 + 3], d0);  d1 = fmaf(b.w, wl[i4 * 4 + 3], d1);
        }
        float m0 = jvalid ? d0 : -1e30f;
        float m1 = jvalid ? d1 : -1e30f;
#pragma unroll
        for (int off = 32; off; off >>= 1) {
          m0 = fmaxf(m0, __shfl_xor(m0, off));
          m1 = fmaxf(m1, __shfl_xor(m1, off));
        }
        float e0 = jvalid ? expf(d0 - m0) : 0.f;
        float e1 = jvalid ? expf(d1 - m1) : 0.f;
        float s0 = e0, s1 = e1;
#pragma unroll
        for (int off = 32; off; off >>= 1) {
          s0 += __shfl_xor(s0, off);
          s1 += __shfl_xor(s1, off);
        }
        float l0 = m0 + logf(s0);
        float l1 = m1 + logf(s1);
        int n0 = nwbase + ns, n1 = n0 + 1;
        if (jvalid) {
          if (n0 < N_NODES) outp[(size_t)n0 * OUT_FEAT + lane] = d0 - l0;
          if (n1 < N_NODES) outp[(size_t)n1 * OUT_FEAT + lane] = d1 - l1;
        }
      }
    }
  }
}

// ---------------------------------------------------------------- launch
extern "C" void kernel_launch(void* const* d_in, const int* in_sizes, int n_in,
                              void* d_out, int out_size, void* d_ws, size_t ws_size,
                              hipStream_t stream) {
  (void)in_sizes; (void)n_in; (void)out_size; (void)ws_size;
  const float* x    = (const float*)d_in[0];
  const int*   erow = (const int*)d_in[1];
  const int*   ecol = (const int*)d_in[2];
  const float* ew   = (const float*)d_in[3];
  const float* W_in = (const float*)d_in[4];
  const float* b_in = (const float*)d_in[5];
  const float* c1   = (const float*)d_in[6];
  const float* c2   = (const float*)d_in[7];
  const float* Wout = (const float*)d_in[8];
  float* out = (float*)d_out;

  float* h0 = (float*)d_ws;          // lin_in output / fused1 gather source
  float* h1 = h0 + NELEM;            // fused1 output / fused2 gather source

  // x buffer (12.8M words, 51.2MB) is consumed by lin_in, then reused:
  unsigned* xw     = (unsigned*)(void*)x;
  unsigned* Brep1  = xw;                     // [0, 32768)
  unsigned* Brep2  = xw + 32768;             // [32768, 65536)
  int*      btail  = (int*)(xw + 65536);     // 98
  int*      ctrs   = (int*)(xw + 65792);     // 2 persistent-tile counters
  int*      rowptr = (int*)(xw + 66048);     // 100001
  uint2*    pack1  = (uint2*)(xw + 262144);  // 98*18432 uint2 (ends 3,874,816)
  uint2*    pack2  = (uint2*)(xw + 3932160); // 1.6M uint2 (ends 7,132,160)

  prep_kernel<<<6507, 256, 0, stream>>>(x, W_in, b_in, h0, c1, c2,
                                        Brep1, Brep2, btail, ctrs);
  bin_kernel<<<BIN_BLOCKS, 256, 0, stream>>>(erow, ecol, ew, btail, pack1);
  bucket_finalize_kernel<<<NB, 256, 0, stream>>>(btail, pack1, rowptr, pack2);

  fused_spmm_kan_kernel<0><<<FGRID, 256, 0, stream>>>(
      rowptr, pack2, h0, Brep1, h1, nullptr, ctrs + 0);
  fused_spmm_kan_kernel<1><<<FGRID, 256, 0, stream>>>(
      rowptr, pack2, h1, Brep2, out, Wout, ctrs + 1);
}

// Round 12
// 417.725 us; speedup vs baseline: 1.2397x; 1.2397x over previous
//
#include <hip/hip_runtime.h>
#include <hip/hip_bf16.h>
#include <string.h>

// KanGNN. Inputs f32 + int32, output f32.
// R22 = R20 fused kernel (non-persistent; R21's while-loop made the
// compiler hoist loop-invariants (wl: 64 VGPR) across the tile loop and
// spill per-tile arrays -> 150MB/dispatch scratch traffic, 123->196us)
// + R21's prep merge kept (lin_in + repack x2 + binit in one launch; 5
// launches total).
// R20: fused spmm+kan(+final), ping-pong h0->h1. R18/19: spmm 4x unroll.
// R17: final W-in-registers. R16: async global_load_lds B staging.
// R13/14: lane-local A build. R11: binned counting-sort CSR build.

#define N_NODES 100000
#define IN_FEAT 128
#define HID 64
#define OUT_FEAT 40
#define NGRID 8
#define N_EDGES 1600000
#define NELEM (N_NODES * HID)

#define NB 98            // buckets: row >> 10
#define CAP 18432        // per-bucket capacity (mean 16384, sigma ~127)
#define BCHUNK 4096      // edges per bin block
#define BIN_BLOCKS ((N_EDGES + BCHUNK - 1) / BCHUNK)   // 391
#define NTILES ((N_NODES + 63) / 64)                   // 1563

using short8 = __attribute__((ext_vector_type(8))) short;
using floatx4 = __attribute__((ext_vector_type(4))) float;
using uintx4 = __attribute__((ext_vector_type(4))) unsigned;

// async 16B/lane global->LDS; lds dest = wave-uniform base + lane*16
#define GLOAD_LDS16(gp, lp)                                                   \
  __builtin_amdgcn_global_load_lds(                                           \
      (const __attribute__((address_space(1))) unsigned*)(gp),                \
      (__attribute__((address_space(3))) unsigned*)(lp), 16, 0, 0)

// f32 -> bf16 RNE, packed pair (lo = c, hi = s)
__device__ __forceinline__ unsigned pack_bf16x2(float c, float s) {
  unsigned uc = __float_as_uint(c);
  unsigned us = __float_as_uint(s);
  uc += 0x7fffu + ((uc >> 16) & 1u);
  us += 0x7fffu + ((us >> 16) & 1u);
  return (uc >> 16) | (us & 0xffff0000u);
}

// same RNE conversion via v_cvt_pk_bf16_f32 (1 instr instead of ~11)
__device__ __forceinline__ unsigned cvtpk_bf16x2(float c, float s) {
  __hip_bfloat162 p = __float22bfloat162_rn(make_float2(c, s));
  unsigned r;
  memcpy(&r, &p, 4);
  return r;
}

// ---------------------------------------------------------------- prep (merged)
// blocks [0,6250): lin_in; [6250,6506): repack c1/c2; 6506: btail.
__global__ __launch_bounds__(256) void prep_kernel(
    const float* __restrict__ x, const float* __restrict__ W,
    const float* __restrict__ b, float* __restrict__ h,
    const float* __restrict__ c1, const float* __restrict__ c2,
    unsigned* __restrict__ Brep1, unsigned* __restrict__ Brep2,
    int* __restrict__ btail) {
  __shared__ __align__(16) float xs[16 * IN_FEAT];   // 8 KB
  int t = threadIdx.x;
  int nb = blockIdx.x;
  if (nb < 6250) {
    // ---- lin_in ----
    const float4* xsrc = (const float4*)(x + (size_t)nb * 16 * IN_FEAT);
    float4* xd = (float4*)xs;
    xd[t] = xsrc[t];
    xd[t + 256] = xsrc[t + 256];
    __syncthreads();
    int lane = t & 63, wv = t >> 6;
    float bj = b[lane];
    float a0 = bj, a1 = bj, a2 = bj, a3 = bj;
    const float* xr = xs + wv * 4 * IN_FEAT;
    const float* Wj = W + lane;
#pragma unroll 4
    for (int i4 = 0; i4 < 32; i4++) {
      float4 x0 = *(const float4*)(xr + 0 * IN_FEAT + i4 * 4);
      float4 x1 = *(const float4*)(xr + 1 * IN_FEAT + i4 * 4);
      float4 x2 = *(const float4*)(xr + 2 * IN_FEAT + i4 * 4);
      float4 x3 = *(const float4*)(xr + 3 * IN_FEAT + i4 * 4);
      float w0 = Wj[(i4 * 4 + 0) * HID];
      float w1 = Wj[(i4 * 4 + 1) * HID];
      float w2 = Wj[(i4 * 4 + 2) * HID];
      float w3 = Wj[(i4 * 4 + 3) * HID];
      a0 = fmaf(x0.x, w0, a0); a0 = fmaf(x0.y, w1, a0); a0 = fmaf(x0.z, w2, a0); a0 = fmaf(x0.w, w3, a0);
      a1 = fmaf(x1.x, w0, a1); a1 = fmaf(x1.y, w1, a1); a1 = fmaf(x1.z, w2, a1); a1 = fmaf(x1.w, w3, a1);
      a2 = fmaf(x2.x, w0, a2); a2 = fmaf(x2.y, w1, a2); a2 = fmaf(x2.z, w2, a2); a2 = fmaf(x2.w, w3, a2);
      a3 = fmaf(x3.x, w0, a3); a3 = fmaf(x3.y, w1, a3); a3 = fmaf(x3.z, w2, a3); a3 = fmaf(x3.w, w3, a3);
    }
    size_t nbase = (size_t)nb * 16 + wv * 4;
    h[(nbase + 0) * HID + lane] = a0;
    h[(nbase + 1) * HID + lane] = a1;
    h[(nbase + 2) * HID + lane] = a2;
    h[(nbase + 3) * HID + lane] = a3;
  } else if (nb < 6506) {
    // ---- repack (R16 layout; identical math) ----
    int rb = nb - 6250;                     // 0..255
    const float* coeffs = (rb < 128) ? c1 : c2;
    unsigned* Brep = (rb < 128) ? Brep1 : Brep2;
    int idx = (rb & 127) * 256 + t;         // 0..32767
    int ch = idx >> 13;
    int rem = idx & 8191;
    int blk = rem >> 8;
    int jt = blk >> 3, ks = blk & 7;
    int rem2 = rem & 255;
    int ls = rem2 >> 2;
    int quad = ls >> 4, m_n = ls & 15;
    int jj = rem2 & 3;
    int j = jt * 16 + m_n;
    int r = ks >> 1, km1 = ((ks & 1) << 2) | jj;
    int i = ch * 16 + quad * 4 + r;
    int ws = i * 8 + km1;
    float cc0 = coeffs[(size_t)j * 512 + ws];
    float cc1 = coeffs[32768 + (size_t)j * 512 + ws];
    Brep[idx] = pack_bf16x2(cc0, cc1);
  } else {
    if (t < NB) btail[t] = t * CAP;
  }
}

// ---------------------------------------------------------------- CSR build (R11)
// Pass 1: coarse-bucket counting sort.
__global__ __launch_bounds__(256) void bin_kernel(
    const int* __restrict__ row, const int* __restrict__ col,
    const float* __restrict__ w, int* __restrict__ btail,
    uint2* __restrict__ pack1) {
  __shared__ __align__(16) uint2 stage[BCHUNK];   // 32 KB
  __shared__ int bcnt[NB];
  __shared__ int lbase[NB];
  __shared__ int gbase[NB];
  __shared__ int lcur[NB];
  __shared__ int sc[128];
  int t = threadIdx.x;
  int e0 = blockIdx.x * BCHUNK;
  if (t < NB) bcnt[t] = 0;
  __syncthreads();
  int rloc[16];
#pragma unroll
  for (int q = 0; q < 16; q++) {
    int e = e0 + q * 256 + t;
    int r = (e < N_EDGES) ? row[e] : -1;
    rloc[q] = r;
    if (r >= 0) atomicAdd(&bcnt[r >> 10], 1);
  }
  __syncthreads();
  int c = (t < NB) ? bcnt[t] : 0;
  if (t < 128) sc[t] = c;
  __syncthreads();
  int v = c;
#pragma unroll
  for (int off = 1; off < 128; off <<= 1) {
    int add = (t >= off && t < 128) ? sc[t - off] : 0;
    __syncthreads();
    if (t < 128) sc[t] = v = v + add;
    __syncthreads();
  }
  if (t < NB) {
    lbase[t] = v - c;
    lcur[t] = v - c;
    gbase[t] = atomicAdd(&btail[t], c);
  }
  __syncthreads();
#pragma unroll
  for (int q = 0; q < 16; q++) {
    int e = e0 + q * 256 + t;
    int r = rloc[q];
    if (r >= 0) {
      int p = atomicAdd(&lcur[r >> 10], 1);
      unsigned key = ((unsigned)(r & 1023) << 17) | (unsigned)col[e];
      stage[p] = make_uint2(key, __float_as_uint(w[e]));
    }
  }
  __syncthreads();
  int wv = t >> 6, lane = t & 63;
  for (int b = wv; b < NB; b += 4) {
    int len = bcnt[b], src = lbase[b];
    uint2* dst = pack1 + (size_t)gbase[b];
    for (int i = lane; i < len; i += 64)
      dst[i] = stage[src + i];
  }
}

// Pass 2: one block per bucket -> rowptr + exact scatter.
__global__ __launch_bounds__(256) void bucket_finalize_kernel(
    const int* __restrict__ btail, const uint2* __restrict__ pack1,
    int* __restrict__ rowptr, uint2* __restrict__ pack2) {
  __shared__ int rcnt[1024];
  __shared__ int sc[256];
  __shared__ int binfo[2];
  int b = blockIdx.x, t = threadIdx.x;
  if (t < NB) sc[t] = btail[t] - t * CAP;   // per-bucket counts
  rcnt[t] = 0; rcnt[t + 256] = 0; rcnt[t + 512] = 0; rcnt[t + 768] = 0;
  __syncthreads();
  if (t == 0) {
    int base = 0;
    for (int i = 0; i < b; i++) base += sc[i];
    binfo[0] = base;
    binfo[1] = sc[b];
  }
  __syncthreads();
  int base = binfo[0], len = binfo[1];
  const uint2* rec = pack1 + (size_t)b * CAP;
  for (int i = t; i < len; i += 256)
    atomicAdd(&rcnt[rec[i].x >> 17], 1);
  __syncthreads();
  int c0 = rcnt[4 * t], c1 = rcnt[4 * t + 1], c2 = rcnt[4 * t + 2], c3 = rcnt[4 * t + 3];
  int s4 = c0 + c1 + c2 + c3;
  sc[t] = s4;
  __syncthreads();
  int v = s4;
#pragma unroll
  for (int off = 1; off < 256; off <<= 1) {
    int add = (t >= off) ? sc[t - off] : 0;
    __syncthreads();
    sc[t] = v = v + add;
    __syncthreads();
  }
  int excl = v - s4;
  int p0 = base + excl;
  int p1 = p0 + c0, p2 = p1 + c1, p3 = p2 + c2;
  int r0 = (b << 10) + 4 * t;
  if (r0 + 0 < N_NODES) rowptr[r0 + 0] = p0;
  if (r0 + 1 < N_NODES) rowptr[r0 + 1] = p1;
  if (r0 + 2 < N_NODES) rowptr[r0 + 2] = p2;
  if (r0 + 3 < N_NODES) rowptr[r0 + 3] = p3;
  rcnt[4 * t] = p0; rcnt[4 * t + 1] = p1; rcnt[4 * t + 2] = p2; rcnt[4 * t + 3] = p3;
  __syncthreads();
  for (int i = t; i < len; i += 256) {
    uint2 p = rec[i];
    int pos = atomicAdd(&rcnt[p.x >> 17], 1);
    pack2[pos] = make_uint2(p.x & 0x1FFFFu, p.y);
  }
  if (b == NB - 1 && t == 0) rowptr[N_NODES] = N_EDGES;
}

// ---------------------------------------------------------------- fused spmm + KAN (+ final)
// One tile per block (R20 structure — no persistent loop, no spills).
template <int DO_FINAL>
__global__ __launch_bounds__(256, 4) void fused_spmm_kan_kernel(
    const int* __restrict__ rowptr, const uint2* __restrict__ pack,
    const float* __restrict__ hin, const unsigned* __restrict__ Brep,
    float* __restrict__ outp, const float* __restrict__ Wout) {
  __shared__ __align__(16) unsigned Bs[2][2048];   // 2 x 8 KB
  __shared__ __align__(16) float s_tile[64 * 64];  // 16 KB
  int t = threadIdx.x;
  int lane = t & 63, wv = t >> 6;
  int nb = blockIdx.x;
  const char* Gb = (const char*)Brep;

  // issue quarter 0 (ch0,jt0) staging now; latency hides under the gathers
#pragma unroll
  for (int i = 0; i < 2; i++) {
    int c = wv + 4 * i;
    GLOAD_LDS16(Gb + c * 1024 + lane * 16, (char*)&Bs[0][0] + c * 1024);
  }

  // ---- phase 1: spmm for rows nb*64 + wv*16 + 0..15 ----
  {
    int rpi = nb * 64 + wv * 16 + lane;
    int rp = 0;
    if (lane < 17) rp = rowptr[rpi < N_NODES ? rpi : N_NODES];  // rowptr[N]=E
    int slot = lane >> 4, f4 = lane & 15;
    const float4* h4 = (const float4*)hin;
    const unsigned long long* packq = (const unsigned long long*)pack;
    for (int i = 0; i < 16; i++) {
      int beg = __shfl(rp, i), end = __shfl(rp, i + 1);
      float4 v = make_float4(0.f, 0.f, 0.f, 0.f);
      for (int e = beg; e < end; e += 16) {
        int i0 = e + slot, i1 = i0 + 4, i2 = i0 + 8, i3 = i0 + 12;
        int c0 = i0 < end ? i0 : end - 1;
        int c1 = i1 < end ? i1 : end - 1;
        int c2 = i2 < end ? i2 : end - 1;
        int c3 = i3 < end ? i3 : end - 1;
        unsigned long long p0 = __builtin_nontemporal_load(packq + c0);
        unsigned long long p1 = __builtin_nontemporal_load(packq + c1);
        unsigned long long p2 = __builtin_nontemporal_load(packq + c2);
        unsigned long long p3 = __builtin_nontemporal_load(packq + c3);
        float4 h0 = h4[(size_t)(unsigned)p0 * 16 + f4];
        float4 h1 = h4[(size_t)(unsigned)p1 * 16 + f4];
        float4 h2 = h4[(size_t)(unsigned)p2 * 16 + f4];
        float4 h3 = h4[(size_t)(unsigned)p3 * 16 + f4];
        float w0 = (i0 < end) ? __uint_as_float((unsigned)(p0 >> 32)) : 0.f;
        float w1 = (i1 < end) ? __uint_as_float((unsigned)(p1 >> 32)) : 0.f;
        float w2 = (i2 < end) ? __uint_as_float((unsigned)(p2 >> 32)) : 0.f;
        float w3 = (i3 < end) ? __uint_as_float((unsigned)(p3 >> 32)) : 0.f;
        v.x = fmaf(w0, h0.x, v.x); v.y = fmaf(w0, h0.y, v.y);
        v.z = fmaf(w0, h0.z, v.z); v.w = fmaf(w0, h0.w, v.w);
        v.x = fmaf(w1, h1.x, v.x); v.y = fmaf(w1, h1.y, v.y);
        v.z = fmaf(w1, h1.z, v.z); v.w = fmaf(w1, h1.w, v.w);
        v.x = fmaf(w2, h2.x, v.x); v.y = fmaf(w2, h2.y, v.y);
        v.z = fmaf(w2, h2.z, v.z); v.w = fmaf(w2, h2.w, v.w);
        v.x = fmaf(w3, h3.x, v.x); v.y = fmaf(w3, h3.y, v.y);
        v.z = fmaf(w3, h3.z, v.z); v.w = fmaf(w3, h3.w, v.w);
      }
#pragma unroll
      for (int off = 16; off < 64; off <<= 1) {
        v.x += __shfl_xor(v.x, off);
        v.y += __shfl_xor(v.y, off);
        v.z += __shfl_xor(v.z, off);
        v.w += __shfl_xor(v.w, off);
      }
      if (slot == 0)
        *(float4*)&s_tile[(wv * 16 + i) * 64 + f4 * 4] = v;
    }
  }
  __syncthreads();   // s_tile complete

  // ---- phase 2: KAN ----
  int m_n = lane & 15, quad = lane >> 4;
  int node_sub = wv * 16 + m_n;
  float4 sv[4];
#pragma unroll
  for (int ch = 0; ch < 4; ch++)
    sv[ch] = *(const float4*)&s_tile[node_sub * 64 + ch * 16 + quad * 4];

  floatx4 acc[4];
#pragma unroll
  for (int jt = 0; jt < 4; jt++) acc[jt] = (floatx4){0.f, 0.f, 0.f, 0.f};
  short8 afr[8];

#pragma unroll
  for (int q = 0; q < 16; q++) {
    // drain this quarter's staging loads; all waves sync
    asm volatile("s_waitcnt vmcnt(0)" ::: "memory");
    __syncthreads();
    if (q < 15) {
      int qq = q + 1;
      const char* gsrc = Gb + (qq >> 2) * 32768 + (qq & 3) * 8192;
      char* ldst = (char*)&Bs[qq & 1][0];
#pragma unroll
      for (int i = 0; i < 2; i++) {
        int c = wv + 4 * i;
        GLOAD_LDS16(gsrc + c * 1024 + lane * 16, ldst + c * 1024);
      }
    }
    if ((q & 3) == 0) {   // build A fragments at the start of each ch
      int ch = q >> 2;
      float ss[4] = {sv[ch].x, sv[ch].y, sv[ch].z, sv[ch].w};
#pragma unroll
      for (int r = 0; r < 4; r++) {
        float s1, c1;
        __sincosf(ss[r], &s1, &c1);
        float ck = c1, sk = s1;
        unsigned wbuf[8];
#pragma unroll
        for (int km1 = 0; km1 < 8; km1++) {
          wbuf[km1] = cvtpk_bf16x2(ck, sk);
          float cn = fmaf(ck, c1, -sk * s1);
          float sn = fmaf(sk, c1, ck * s1);
          ck = cn; sk = sn;
        }
        uintx4 lo = (uintx4){wbuf[0], wbuf[1], wbuf[2], wbuf[3]};
        uintx4 hi = (uintx4){wbuf[4], wbuf[5], wbuf[6], wbuf[7]};
        memcpy(&afr[2 * r], &lo, 16);
        memcpy(&afr[2 * r + 1], &hi, 16);
      }
    }
    const char* Bb = (const char*)&Bs[q & 1][0];
    int jt = q & 3;
#pragma unroll
    for (int ks = 0; ks < 8; ks++) {
      short8 bf = *reinterpret_cast<const short8*>(Bb + ks * 1024 + lane * 16);
      acc[jt] = __builtin_amdgcn_mfma_f32_16x16x32_bf16(afr[ks], bf, acc[jt], 0, 0, 0);
    }
  }

  if (DO_FINAL == 0) {
    // epilogue: D col=m_n (j), row=quad*4+reg (node) -> h_out global
#pragma unroll
    for (int jt = 0; jt < 4; jt++) {
#pragma unroll
      for (int reg = 0; reg < 4; reg++) {
        int node = nb * 64 + wv * 16 + quad * 4 + reg;
        if (node < N_NODES)
          outp[(size_t)node * HID + jt * 16 + m_n] = acc[jt][reg];
      }
    }
  } else {
    // acc -> s_tile (s_tile dead since sv prefetch; own-wave rows only)
#pragma unroll
    for (int jt = 0; jt < 4; jt++) {
#pragma unroll
      for (int reg = 0; reg < 4; reg++)
        s_tile[(wv * 16 + quad * 4 + reg) * 64 + jt * 16 + m_n] = acc[jt][reg];
    }
    __syncthreads();
    // ---- final phase (R17): W column in registers, 2 nodes in flight ----
    bool jvalid = lane < OUT_FEAT;
    int jc = jvalid ? lane : 0;
    float wl[HID];
#pragma unroll
    for (int i2 = 0; i2 < HID; i2++)
      wl[i2] = Wout[i2 * OUT_FEAT + jc];
    int nwbase = nb * 64 + wv * 16;
    for (int ns = 0; ns < 16; ns += 2) {
      const float* h0p = &s_tile[(wv * 16 + ns) * 64];
      const float* h1p = h0p + 64;
      float d0 = 0.f, d1 = 0.f;
#pragma unroll
      for (int i4 = 0; i4 < 16; i4++) {
        float4 a = *(const float4*)(h0p + i4 * 4);
        float4 b = *(const float4*)(h1p + i4 * 4);
        d0 = fmaf(a.x, wl[i4 * 4 + 0], d0);  d1 = fmaf(b.x, wl[i4 * 4 + 0], d1);
        d0 = fmaf(a.y, wl[i4 * 4 + 1], d0);  d1 = fmaf(b.y, wl[i4 * 4 + 1], d1);
        d0 = fmaf(a.z, wl[i4 * 4 + 2], d0);  d1 = fmaf(b.z, wl[i4 * 4 + 2], d1);
        d0 = fmaf(a.w, wl[i4 * 4 + 3], d0);  d1 = fmaf(b.w, wl[i4 * 4 + 3], d1);
      }
      float m0 = jvalid ? d0 : -1e30f;
      float m1 = jvalid ? d1 : -1e30f;
#pragma unroll
      for (int off = 32; off; off >>= 1) {
        m0 = fmaxf(m0, __shfl_xor(m0, off));
        m1 = fmaxf(m1, __shfl_xor(m1, off));
      }
      float e0 = jvalid ? expf(d0 - m0) : 0.f;
      float e1 = jvalid ? expf(d1 - m1) : 0.f;
      float s0 = e0, s1 = e1;
#pragma unroll
      for (int off = 32; off; off >>= 1) {
        s0 += __shfl_xor(s0, off);
        s1 += __shfl_xor(s1, off);
      }
      float l0 = m0 + logf(s0);
      float l1 = m1 + logf(s1);
      int n0 = nwbase + ns, n1 = n0 + 1;
      if (jvalid) {
        if (n0 < N_NODES) outp[(size_t)n0 * OUT_FEAT + lane] = d0 - l0;
        if (n1 < N_NODES) outp[(size_t)n1 * OUT_FEAT + lane] = d1 - l1;
      }
    }
  }
}

// ---------------------------------------------------------------- launch
extern "C" void kernel_launch(void* const* d_in, const int* in_sizes, int n_in,
                              void* d_out, int out_size, void* d_ws, size_t ws_size,
                              hipStream_t stream) {
  (void)in_sizes; (void)n_in; (void)out_size; (void)ws_size;
  const float* x    = (const float*)d_in[0];
  const int*   erow = (const int*)d_in[1];
  const int*   ecol = (const int*)d_in[2];
  const float* ew   = (const float*)d_in[3];
  const float* W_in = (const float*)d_in[4];
  const float* b_in = (const float*)d_in[5];
  const float* c1   = (const float*)d_in[6];
  const float* c2   = (const float*)d_in[7];
  const float* Wout = (const float*)d_in[8];
  float* out = (float*)d_out;

  float* h0 = (float*)d_ws;          // lin_in output / fused1 gather source
  float* h1 = h0 + NELEM;            // fused1 output / fused2 gather source

  // x buffer (12.8M words, 51.2MB) is consumed by lin_in, then reused:
  unsigned* xw     = (unsigned*)(void*)x;
  unsigned* Brep1  = xw;                     // [0, 32768)
  unsigned* Brep2  = xw + 32768;             // [32768, 65536)
  int*      btail  = (int*)(xw + 65536);     // 98
  int*      rowptr = (int*)(xw + 66048);     // 100001
  uint2*    pack1  = (uint2*)(xw + 262144);  // 98*18432 uint2 (ends 3,874,816)
  uint2*    pack2  = (uint2*)(xw + 3932160); // 1.6M uint2 (ends 7,132,160)

  prep_kernel<<<6507, 256, 0, stream>>>(x, W_in, b_in, h0, c1, c2,
                                        Brep1, Brep2, btail);
  bin_kernel<<<BIN_BLOCKS, 256, 0, stream>>>(erow, ecol, ew, btail, pack1);
  bucket_finalize_kernel<<<NB, 256, 0, stream>>>(btail, pack1, rowptr, pack2);

  fused_spmm_kan_kernel<0><<<NTILES, 256, 0, stream>>>(
      rowptr, pack2, h0, Brep1, h1, nullptr);
  fused_spmm_kan_kernel<1><<<NTILES, 256, 0, stream>>>(
      rowptr, pack2, h1, Brep2, out, Wout);
}